// Round 1
// baseline (106.061 us; speedup 1.0000x reference)
//
#include <hip/hip_runtime.h>
#include <hip/hip_bf16.h>

// FilterbankLinear: out[b, j*8+o] = sum_{c,t} x[b,c,s_j+t] * w[j*8.. , c*32+t]
// s_j = j for j<4063, s_4063 = 4064.
// One wave per window: M=32 (two 16-row MFMA tiles), N=8 (of 16, cols 8-15 dup),
// K=672 as 21 steps of 32 (one input channel per K-step). bf16 MFMA, fp32 accum.

#define NF 4096         // IN_FEATURES
#define NC 21           // IN_CHANNELS
#define WIN 32          // WINDOW
#define OC 8            // OUT_CHANNELS
#define NWIN 4064       // N_WIN
#define NKTOT (OC * NWIN)   // 32512
#define DD (NC * WIN)       // 672

typedef short short8 __attribute__((ext_vector_type(8)));
typedef float f32x4 __attribute__((ext_vector_type(4)));

static __device__ __forceinline__ short f2bf(float f) {
  __bf16 h = (__bf16)f;                  // RNE convert; compiler pairs into v_cvt_pk_bf16_f32
  return __builtin_bit_cast(short, h);
}

static __device__ __forceinline__ short8 pack8(float a, float b, float c, float d,
                                               float e, float f, float g, float h) {
  short8 v;
  v[0] = f2bf(a); v[1] = f2bf(b); v[2] = f2bf(c); v[3] = f2bf(d);
  v[4] = f2bf(e); v[5] = f2bf(f); v[6] = f2bf(g); v[7] = f2bf(h);
  return v;
}

__global__ __launch_bounds__(256) void fb_mfma(const float* __restrict__ x,
                                               const float* __restrict__ w,
                                               float* __restrict__ out) {
  const int lane = threadIdx.x & 63;
  const int j = (blockIdx.x * 256 + threadIdx.x) >> 6;   // wave id == window
  const int s = (j == NWIN - 1) ? (NF - WIN) : j;        // window start
  const int n = lane & 15;                               // MFMA row/col index
  const int k0 = (lane >> 4) << 3;                       // k-slice base: 0,8,16,24
  const int r = s & 3;                                   // uniform misalignment
  const int a4 = (s + k0) >> 2;                          // aligned float4 index in x row

  // weight row for this lane's output column (lanes 8-15 duplicate 0-7: same lines)
  const float* wrow = w + (size_t)j * (OC * DD) + (size_t)(n & 7) * DD + k0;
  // x row bases for the two b-tiles
  const float* xr0 = x + (size_t)n * NC * NF;
  const float* xr1 = x + (size_t)(n + 16) * NC * NF;

  f32x4 acc0 = {0.f, 0.f, 0.f, 0.f};
  f32x4 acc1 = {0.f, 0.f, 0.f, 0.f};

  for (int kk = 0; kk < NC; ++kk) {
    // ---- B fragment: 8 consecutive k of weight row (16B-aligned) ----
    const float4* wp = (const float4*)(wrow + kk * WIN);
    float4 b0 = wp[0], b1 = wp[1];
    short8 fb = pack8(b0.x, b0.y, b0.z, b0.w, b1.x, b1.y, b1.z, b1.w);

    // ---- A fragments: 8 consecutive window elems from aligned float4 cover ----
    const float4* p0 = (const float4*)(xr0 + (size_t)kk * NF) + a4;
    const float4* p1 = (const float4*)(xr1 + (size_t)kk * NF) + a4;
    float4 f0 = p0[0], f1 = p0[1];
    float4 g0 = p1[0], g1 = p1[1];
    short8 fa0, fa1;
    if (r == 0) {
      fa0 = pack8(f0.x, f0.y, f0.z, f0.w, f1.x, f1.y, f1.z, f1.w);
      fa1 = pack8(g0.x, g0.y, g0.z, g0.w, g1.x, g1.y, g1.z, g1.w);
    } else {
      float4 f2 = p0[2], g2 = p1[2];   // only safe/needed when r>0 (bounds-checked)
      if (r == 1) {
        fa0 = pack8(f0.y, f0.z, f0.w, f1.x, f1.y, f1.z, f1.w, f2.x);
        fa1 = pack8(g0.y, g0.z, g0.w, g1.x, g1.y, g1.z, g1.w, g2.x);
      } else if (r == 2) {
        fa0 = pack8(f0.z, f0.w, f1.x, f1.y, f1.z, f1.w, f2.x, f2.y);
        fa1 = pack8(g0.z, g0.w, g1.x, g1.y, g1.z, g1.w, g2.x, g2.y);
      } else {
        fa0 = pack8(f0.w, f1.x, f1.y, f1.z, f1.w, f2.x, f2.y, f2.z);
        fa1 = pack8(g0.w, g1.x, g1.y, g1.z, g1.w, g2.x, g2.y, g2.z);
      }
    }
    acc0 = __builtin_amdgcn_mfma_f32_16x16x32_bf16(fa0, fb, acc0, 0, 0, 0);
    acc1 = __builtin_amdgcn_mfma_f32_16x16x32_bf16(fa1, fb, acc1, 0, 0, 0);
  }

  // C/D: col = lane&15 (=o, keep <8), row = (lane>>4)*4 + reg (=b within tile)
  if (n < 8) {
    const int brow = (lane >> 4) * 4;
    #pragma unroll
    for (int e = 0; e < 4; ++e) {
      out[(size_t)(brow + e) * NKTOT + (size_t)j * OC + n] = acc0[e];
      out[(size_t)(brow + e + 16) * NKTOT + (size_t)j * OC + n] = acc1[e];
    }
  }
}

extern "C" void kernel_launch(void* const* d_in, const int* in_sizes, int n_in,
                              void* d_out, int out_size, void* d_ws, size_t ws_size,
                              hipStream_t stream) {
  const float* x = (const float*)d_in[0];
  const float* w = (const float*)d_in[1];
  float* out = (float*)d_out;
  dim3 grid(NWIN / 4), block(256);   // 4 waves/block, 1 window/wave
  hipLaunchKernelGGL(fb_mfma, grid, block, 0, stream, x, w, out);
}

// Round 2
// 63.502 us; speedup vs baseline: 1.6702x; 1.6702x over previous
//
#include <hip/hip_runtime.h>
#include <hip/hip_bf16.h>

// FilterbankLinear: out[b, j*8+o] = sum_{c,t} x[b,c,s_j+t] * w[j*8+o, c*32+t]
// s_j = j for j<4063, s_4063 = 4064.
// One block (3 waves, 192 thr) per window. Wave wv handles channels [7wv, 7wv+7).
// M=32 batches as two 16-row MFMA tiles, N=8 (cols 8-15 dup-read), K=32/channel.
// Depth-2 software pipeline (next channel's 6 loads in flight over current MFMA).
// LDS partial reduce across the 3 waves, deterministic order.

#define NF 4096         // IN_FEATURES
#define NC 21           // IN_CHANNELS
#define WIN 32          // WINDOW
#define OC 8            // OUT_CHANNELS
#define NWIN 4064       // N_WIN
#define NKTOT (OC * NWIN)   // 32512
#define DD (NC * WIN)       // 672
#define CPW 7           // channels per wave
#define NWV 3           // waves per block

typedef short short8 __attribute__((ext_vector_type(8)));
typedef float f32x4 __attribute__((ext_vector_type(4)));
// 4-byte-aligned float4: gfx950 global loads need only dword alignment,
// so 8 consecutive floats at any dword offset = two dwordx4 loads, no branch.
typedef float f4u __attribute__((ext_vector_type(4), aligned(4)));

static __device__ __forceinline__ short f2bf(float f) {
  __bf16 h = (__bf16)f;
  return __builtin_bit_cast(short, h);
}

static __device__ __forceinline__ short8 pack2(f4u a, f4u b) {
  short8 v;
  v[0] = f2bf(a[0]); v[1] = f2bf(a[1]); v[2] = f2bf(a[2]); v[3] = f2bf(a[3]);
  v[4] = f2bf(b[0]); v[5] = f2bf(b[1]); v[6] = f2bf(b[2]); v[7] = f2bf(b[3]);
  return v;
}

__global__ __launch_bounds__(192) void fb_mfma(const float* __restrict__ x,
                                               const float* __restrict__ w,
                                               float* __restrict__ out) {
  __shared__ float plds[NWV * 256];
  const int lane = threadIdx.x & 63;
  const int wv = threadIdx.x >> 6;
  // XCD-chunked swizzle: 508 consecutive windows per XCD for x L2 locality
  const int bid = blockIdx.x;
  const int j = (bid >> 3) + (bid & 7) * (NWIN / 8);
  const int s = (j == NWIN - 1) ? (NF - WIN) : j;
  const int n = lane & 15;
  const int k0 = (lane >> 4) << 3;        // 0,8,16,24

  const float* wp  = w + (size_t)j * (OC * DD) + (size_t)(n & 7) * DD
                       + (size_t)(wv * CPW) * WIN + k0;
  const float* xp0 = x + ((size_t)n * NC + wv * CPW) * NF + s + k0;
  const float* xp1 = xp0 + (size_t)16 * NC * NF;

  f32x4 acc0 = {0.f, 0.f, 0.f, 0.f};
  f32x4 acc1 = {0.f, 0.f, 0.f, 0.f};

  // prologue: channel 0 loads
  f4u cw0 = *(const f4u*)(wp);
  f4u cw1 = *(const f4u*)(wp + 4);
  f4u ca0 = *(const f4u*)(xp0);
  f4u ca1 = *(const f4u*)(xp0 + 4);
  f4u cb0 = *(const f4u*)(xp1);
  f4u cb1 = *(const f4u*)(xp1 + 4);

  #pragma unroll
  for (int t = 0; t < CPW; ++t) {
    f4u nw0, nw1, na0, na1, nb0, nb1;
    if (t < CPW - 1) {   // issue next channel's loads before current compute
      const float* wq  = wp  + (t + 1) * WIN;
      const float* x0q = xp0 + (size_t)(t + 1) * NF;
      const float* x1q = xp1 + (size_t)(t + 1) * NF;
      nw0 = *(const f4u*)(wq);  nw1 = *(const f4u*)(wq + 4);
      na0 = *(const f4u*)(x0q); na1 = *(const f4u*)(x0q + 4);
      nb0 = *(const f4u*)(x1q); nb1 = *(const f4u*)(x1q + 4);
    }
    short8 fb  = pack2(cw0, cw1);
    short8 fa0 = pack2(ca0, ca1);
    short8 fa1 = pack2(cb0, cb1);
    acc0 = __builtin_amdgcn_mfma_f32_16x16x32_bf16(fa0, fb, acc0, 0, 0, 0);
    acc1 = __builtin_amdgcn_mfma_f32_16x16x32_bf16(fa1, fb, acc1, 0, 0, 0);
    cw0 = nw0; cw1 = nw1; ca0 = na0; ca1 = na1; cb0 = nb0; cb1 = nb1;
  }

  // partials -> LDS: idx = tile*128 + row*8 + o
  if (n < 8) {
    const int brow = (lane >> 4) * 4;
    #pragma unroll
    for (int e = 0; e < 4; ++e) {
      plds[wv * 256 +       (brow + e) * 8 + n] = acc0[e];
      plds[wv * 256 + 128 + (brow + e) * 8 + n] = acc1[e];
    }
  }
  __syncthreads();

  // deterministic 3-way reduce + store (wave 0 only)
  if (wv == 0) {
    #pragma unroll
    for (int i = 0; i < 4; ++i) {
      const int idx = i * 64 + lane;
      const float v = plds[idx] + plds[256 + idx] + plds[512 + idx];
      const int b = (idx >> 7) * 16 + ((idx >> 3) & 15);
      const int o = idx & 7;
      out[(size_t)b * NKTOT + (size_t)j * OC + o] = v;
    }
  }
}

extern "C" void kernel_launch(void* const* d_in, const int* in_sizes, int n_in,
                              void* d_out, int out_size, void* d_ws, size_t ws_size,
                              hipStream_t stream) {
  const float* x = (const float*)d_in[0];
  const float* w = (const float*)d_in[1];
  float* out = (float*)d_out;
  dim3 grid(NWIN), block(NWV * 64);
  hipLaunchKernelGGL(fb_mfma, grid, block, 0, stream, x, w, out);
}

// Round 3
// 29.375 us; speedup vs baseline: 3.6105x; 2.1617x over previous
//
#include <hip/hip_runtime.h>
#include <hip/hip_bf16.h>

// FilterbankLinear: out[b, j*8+o] = sum_{c,t} x[b,c,s_j+t] * w[j*8+o, c*32+t]
// s_j = j (j<4063), s_4063 = 4064.
// Block = 8 windows (508 blocks, whole grid resident at 2 blocks/CU), 4 waves.
// Wave handles windows {2wv, 2wv+1} x both 16-batch M-tiles. K = one channel (32).
// x: LDS-staged via coalesced global_load_lds dwordx4 (17-chunk odd row stride ->
//    conflict-free ds_read_b128), double-buffered, 1 barrier/channel.
// w: direct 16B-aligned float4 register prefetch (T14 issue-early), no LDS.

#define NF 4096
#define NC 21
#define WIN 32
#define OC 8
#define NWIN 4064
#define NKTOT (OC * NWIN)
#define DD (NC * WIN)       // 672
#define JB 8
#define NBLK (NWIN / JB)    // 508
#define XROWB 272           // 17 chunks * 16B per x row in LDS
#define XBUFB 9216          // 576 chunks * 16B per buffer

typedef short short8 __attribute__((ext_vector_type(8)));
typedef float f32x4 __attribute__((ext_vector_type(4)));

static __device__ __forceinline__ short f2bf(float f) {
  __bf16 h = (__bf16)f;
  return __builtin_bit_cast(short, h);
}
static __device__ __forceinline__ short8 pk8(float a, float b, float c, float d,
                                             float e, float f, float g, float h) {
  short8 v;
  v[0]=f2bf(a); v[1]=f2bf(b); v[2]=f2bf(c); v[3]=f2bf(d);
  v[4]=f2bf(e); v[5]=f2bf(f); v[6]=f2bf(g); v[7]=f2bf(h);
  return v;
}
// select 8 consecutive floats out of 12 by wave-uniform u (static indices only)
static __device__ __forceinline__ short8 sel8(f32x4 a, f32x4 b, f32x4 c, int u) {
  switch (u & 3) {
    case 0:  return pk8(a[0],a[1],a[2],a[3],b[0],b[1],b[2],b[3]);
    case 1:  return pk8(a[1],a[2],a[3],b[0],b[1],b[2],b[3],c[0]);
    case 2:  return pk8(a[2],a[3],b[0],b[1],b[2],b[3],c[0],c[1]);
    default: return pk8(a[3],b[0],b[1],b[2],b[3],c[0],c[1],c[2]);
  }
}

#define STAGE(GP, I, NB) \
  __builtin_amdgcn_global_load_lds( \
    (const __attribute__((address_space(1))) unsigned int*)(GP), \
    (__attribute__((address_space(3))) unsigned int*)(xlds + (NB)*XBUFB + (I)*1024), \
    16, 0, 0)

__global__ __launch_bounds__(256) void fb_stage(const float* __restrict__ x,
                                                const float* __restrict__ w,
                                                float* __restrict__ out) {
  __shared__ __align__(16) char xlds[2 * XBUFB];
  const int lane = threadIdx.x & 63;
  const int wv   = threadIdx.x >> 6;

  // bijective XCD swizzle (nwg=508: q=63, r=4) — consecutive blocks share an XCD
  const int orig = blockIdx.x;
  const int xcd = orig & 7, idx = orig >> 3;
  const int blk = (xcd < 4 ? xcd * 64 : 256 + (xcd - 4) * 63) + idx;
  const int j0 = blk * JB;
  const int a0 = (j0 < NF - 68) ? j0 : (NF - 68);   // staged span base (4-float aligned)

  const int n  = lane & 15;              // MFMA row/col index
  const int o  = n & 7;                  // output channel (lanes 8-15 dup)
  const int Ck = (lane >> 4) * 2;        // k0/4: chunk offset from k-slice
  const int boff0 = n * XROWB, boff1 = (16 + n) * XROWB;

  const int jg0 = j0 + 2 * wv, jg1 = jg0 + 1;
  const int s1v = (jg1 == NWIN - 1) ? (NF - WIN) : jg1;
  const int rj0 = jg0 - a0, rj1 = s1v - a0;
  const int u0 = rj0 & 3, u1 = rj1 & 3;
  const int Cw0 = rj0 >> 2, Cw1 = rj1 >> 2;

  // x staging thread coords: instrs i = 2wv, 2wv+1, plus i=8 on wave 0
  const int i0 = 2 * wv, i1 = 2 * wv + 1;
  int q0 = i0 * 64 + lane, q1 = i1 * 64 + lane, q2 = 512 + lane;
  if (q2 > 543) q2 = 543;                // clamp tail lanes (dup-write into pad)
  const int b0 = q0 / 17, p0 = q0 - b0 * 17;
  const int b1 = q1 / 17, p1 = q1 - b1 * 17;
  const int b2 = q2 / 17, p2 = q2 - b2 * 17;
  const float* xs0 = x + (size_t)b0 * (NC * NF) + a0 + p0 * 4;
  const float* xs1 = x + (size_t)b1 * (NC * NF) + a0 + p1 * 4;
  const float* xs2 = x + (size_t)b2 * (NC * NF) + a0 + p2 * 4;

  const float* wn0 = w + ((size_t)jg0 * OC + o) * DD + Ck * 4;
  const float* wn1 = w + ((size_t)jg1 * OC + o) * DD + Ck * 4;

  f32x4 acc00 = {0,0,0,0}, acc01 = {0,0,0,0}, acc10 = {0,0,0,0}, acc11 = {0,0,0,0};

  // ---- prologue: stage + load channel 0 ----
  STAGE(xs0, i0, 0); xs0 += NF;
  STAGE(xs1, i1, 0); xs1 += NF;
  if (wv == 0) { STAGE(xs2, 8, 0); xs2 += NF; }
  float4 w0a = *(const float4*)(wn0), w0b = *(const float4*)(wn0 + 4);
  float4 w1a = *(const float4*)(wn1), w1b = *(const float4*)(wn1 + 4);
  wn0 += WIN; wn1 += WIN;
  __syncthreads();

  int buf = 0;
  for (int c = 0; c < NC; ++c) {
    float4 w0an = {0,0,0,0}, w0bn = {0,0,0,0}, w1an = {0,0,0,0}, w1bn = {0,0,0,0};
    if (c < NC - 1) {  // issue next channel's staging + w prefetch before compute
      STAGE(xs0, i0, buf ^ 1); xs0 += NF;
      STAGE(xs1, i1, buf ^ 1); xs1 += NF;
      if (wv == 0) { STAGE(xs2, 8, buf ^ 1); xs2 += NF; }
      w0an = *(const float4*)(wn0); w0bn = *(const float4*)(wn0 + 4);
      w1an = *(const float4*)(wn1); w1bn = *(const float4*)(wn1 + 4);
      wn0 += WIN; wn1 += WIN;
    }
    const char* xb = xlds + buf * XBUFB;
    {   // window 0
      short8 fbw = pk8(w0a.x,w0a.y,w0a.z,w0a.w,w0b.x,w0b.y,w0b.z,w0b.w);
      int off = boff0 + (Cw0 + Ck) * 16;
      f32x4 ra = *(const f32x4*)(xb + off);
      f32x4 rb = *(const f32x4*)(xb + off + 16);
      f32x4 rc = *(const f32x4*)(xb + off + 32);
      acc00 = __builtin_amdgcn_mfma_f32_16x16x32_bf16(sel8(ra,rb,rc,u0), fbw, acc00, 0,0,0);
      off = boff1 + (Cw0 + Ck) * 16;
      ra = *(const f32x4*)(xb + off);
      rb = *(const f32x4*)(xb + off + 16);
      rc = *(const f32x4*)(xb + off + 32);
      acc01 = __builtin_amdgcn_mfma_f32_16x16x32_bf16(sel8(ra,rb,rc,u0), fbw, acc01, 0,0,0);
    }
    {   // window 1
      short8 fbw = pk8(w1a.x,w1a.y,w1a.z,w1a.w,w1b.x,w1b.y,w1b.z,w1b.w);
      int off = boff0 + (Cw1 + Ck) * 16;
      f32x4 ra = *(const f32x4*)(xb + off);
      f32x4 rb = *(const f32x4*)(xb + off + 16);
      f32x4 rc = *(const f32x4*)(xb + off + 32);
      acc10 = __builtin_amdgcn_mfma_f32_16x16x32_bf16(sel8(ra,rb,rc,u1), fbw, acc10, 0,0,0);
      off = boff1 + (Cw1 + Ck) * 16;
      ra = *(const f32x4*)(xb + off);
      rb = *(const f32x4*)(xb + off + 16);
      rc = *(const f32x4*)(xb + off + 32);
      acc11 = __builtin_amdgcn_mfma_f32_16x16x32_bf16(sel8(ra,rb,rc,u1), fbw, acc11, 0,0,0);
    }
    __syncthreads();      // drains vmcnt: buf^1 staged, w prefetch landed
    w0a = w0an; w0b = w0bn; w1a = w1an; w1b = w1bn;
    buf ^= 1;
  }

  if (n < 8) {
    const int m0 = (lane >> 4) * 4;
    #pragma unroll
    for (int e = 0; e < 4; ++e) {
      out[(size_t)(m0 + e)      * NKTOT + (size_t)jg0 * OC + n] = acc00[e];
      out[(size_t)(m0 + e + 16) * NKTOT + (size_t)jg0 * OC + n] = acc01[e];
      out[(size_t)(m0 + e)      * NKTOT + (size_t)jg1 * OC + n] = acc10[e];
      out[(size_t)(m0 + e + 16) * NKTOT + (size_t)jg1 * OC + n] = acc11[e];
    }
  }
}

extern "C" void kernel_launch(void* const* d_in, const int* in_sizes, int n_in,
                              void* d_out, int out_size, void* d_ws, size_t ws_size,
                              hipStream_t stream) {
  const float* x = (const float*)d_in[0];
  const float* w = (const float*)d_in[1];
  float* out = (float*)d_out;
  dim3 grid(NBLK), block(256);
  hipLaunchKernelGGL(fb_stage, grid, block, 0, stream, x, w, out);
}